// Round 8
// baseline (5235.098 us; speedup 1.0000x reference)
//
#include <hip/hip_runtime.h>
#include <math.h>

// ---------------------------------------------------------------------------
// EncNP: tr_pos -> 2x { FPS -> kNN -> LGA -> 2*mean_k -> BN+GELU }
// B=4, N=4096, EMBED=84, K=24.  All f32.
// Index decisions (FPS argmax, kNN top-k) replicate reference arithmetic
// bit-exactly (rn ops, no fma contraction, first-index tie-breaks).
// k_anp(w) + w.mean(-1) == 2*mean_k(w)  (e-scalar cancels) -> w never stored.
//
// R5: FPS v3 — 1024 threads/block (NPT=4), xyz staged in LDS (centroid via
// broadcast read, no coord carrying), pk-only reduction: DPP quad_perm
// xor1/xor2 + row_ror4/8 (VALU), ds_swizzle xor16, shfl xor32. 1 barrier/iter.
// ---------------------------------------------------------------------------

__device__ __forceinline__ float sq3_rn(float dx, float dy, float dz) {
  return __fadd_rn(__fadd_rn(__fmul_rn(dx, dx), __fmul_rn(dy, dy)),
                   __fmul_rn(dz, dz));
}

// max over u64 with DPP lane permutation CTRL (all rows/banks, old=src)
template <int CTRL>
__device__ __forceinline__ unsigned long long max64_dpp(unsigned long long pk) {
  int lo = (int)(unsigned)pk, hi = (int)(unsigned)(pk >> 32);
  unsigned olo = (unsigned)__builtin_amdgcn_update_dpp(lo, lo, CTRL, 0xF, 0xF, false);
  unsigned ohi = (unsigned)__builtin_amdgcn_update_dpp(hi, hi, CTRL, 0xF, 0xF, false);
  unsigned long long o = ((unsigned long long)ohi << 32) | olo;
  return o > pk ? o : pk;
}

// full 64-lane max of packed (dist,idx) u64.
// xor1,xor2: quad_perm; xor4,xor8: row_ror (rotate-reduce == max over row16);
// xor16: ds_swizzle; xor32: shfl.
__device__ __forceinline__ unsigned long long wave_max64(unsigned long long pk) {
  pk = max64_dpp<0xB1>(pk);   // quad_perm [1,0,3,2]  == xor1
  pk = max64_dpp<0x4E>(pk);   // quad_perm [2,3,0,1]  == xor2
  pk = max64_dpp<0x124>(pk);  // row_ror:4
  pk = max64_dpp<0x128>(pk);  // row_ror:8  -> row16 max
  {
    unsigned lo = (unsigned)pk, hi = (unsigned)(pk >> 32);
    unsigned olo = (unsigned)__builtin_amdgcn_ds_swizzle((int)lo, 0x401F);
    unsigned ohi = (unsigned)__builtin_amdgcn_ds_swizzle((int)hi, 0x401F);
    unsigned long long o = ((unsigned long long)ohi << 32) | olo;
    if (o > pk) pk = o;
  }
  {
    unsigned long long o = __shfl_xor(pk, 32);
    if (o > pk) pk = o;
  }
  return pk;
}

// ------------------------------- zero accums -------------------------------
__global__ void zero_kernel(double* p, int n) {
  int i = blockIdx.x * blockDim.x + threadIdx.x;
  if (i < n) p[i] = 0.0;
}

// ------------------------------- tr_pos ------------------------------------
// x0[b,n, d*28 + 2f + s] = sin/cos(100*xyz[b,n,d] / 1000^(f/14))
__global__ void trpos_kernel(const float* __restrict__ xyz, int BN,
                             float* __restrict__ x0) {
  int idx = blockIdx.x * blockDim.x + threadIdx.x;
  if (idx >= BN * 42) return;
  int bn = idx / 42;
  int t = idx - bn * 42;
  int dI = t / 14, f = t - dI * 14;
  float v = xyz[(size_t)bn * 3 + dI];
  float af = expf(6.907755278982137f * (float)f * (1.0f / 14.0f));
  float arg = 100.0f * v / af;
  x0[(size_t)bn * 84 + dI * 28 + 2 * f] = sinf(arg);
  x0[(size_t)bn * 84 + dI * 28 + 2 * f + 1] = cosf(arg);
}

// ------------------------------- FPS ---------------------------------------
// One block (1024 threads) per batch; point p owned by thread p&1023, slot
// p>>10. Exact decision replication: d=((dx^2+dy^2)+dz^2) rn, dist=min,
// global argmax first-index == max over packed (bits(d)<<32 | ~p).
// xyz staged to LDS; centroid fetched by broadcast read (no second barrier).
template <int NPT>  // N == NPT*1024
__global__ __launch_bounds__(1024) void fps_kernel(
    const float* __restrict__ xyz, int N, int G, int* __restrict__ fps_idx,
    float* __restrict__ lc_out) {
  extern __shared__ float sxyz[];  // N*3
  __shared__ unsigned long long wpk[2][16];
  const int b = blockIdx.x, tid = threadIdx.x;
  const float* xb = xyz + (size_t)b * N * 3;
  for (int t = tid; t < N * 3; t += 1024) sxyz[t] = xb[t];
  float px[NPT], py[NPT], pz[NPT], dist[NPT];
#pragma unroll
  for (int i = 0; i < NPT; i++) {
    int p = i * 1024 + tid;
    px[i] = xb[p * 3 + 0];
    py[i] = xb[p * 3 + 1];
    pz[i] = xb[p * 3 + 2];
    dist[i] = 1e10f;
  }
  __syncthreads();  // sxyz ready (read-only hereafter)
  int far = 0;
  float cx = sxyz[0], cy = sxyz[1], cz = sxyz[2];

  for (int g = 0; g < G; ++g) {
    if (tid == 0) {
      fps_idx[b * G + g] = far;
      lc_out[(size_t)(b * G + g) * 3 + 0] = cx;
      lc_out[(size_t)(b * G + g) * 3 + 1] = cy;
      lc_out[(size_t)(b * G + g) * 3 + 2] = cz;
    }
    if (g == G - 1) break;

    // ---- phase A: dist update + thread-local argmax ----
    float bv = -1.0f;
    int bp = 0;
#pragma unroll
    for (int i = 0; i < NPT; i++) {
      float d = sq3_rn(px[i] - cx, py[i] - cy, pz[i] - cz);
      float dm = fminf(dist[i], d);
      dist[i] = dm;
      bool c = dm > bv;  // strict >: ascending p => first max kept
      bv = fmaxf(bv, dm);
      bp = c ? i * 1024 + tid : bp;
    }
    // pack: non-negative f32 bits order-monotonic; ~p => min p on tie.
    unsigned long long pk =
        ((unsigned long long)__float_as_uint(bv) << 32) | (unsigned)(~bp);

    // ---- phase B: 64-lane max, mostly VALU ----
    pk = wave_max64(pk);

    // ---- phase C: cross-wave combine, single barrier, parity dbuf ----
    const int par = g & 1;
    if ((tid & 63) == 0) wpk[par][tid >> 6] = pk;
    __syncthreads();
    unsigned long long m = wpk[par][0];
#pragma unroll
    for (int w = 1; w < 16; w++) {
      unsigned long long o = wpk[par][w];
      if (o > m) m = o;
    }
    far = (int)(~(unsigned)(m & 0xffffffffu));
    cx = sxyz[far * 3 + 0];  // broadcast LDS read
    cy = sxyz[far * 3 + 1];
    cz = sxyz[far * 3 + 2];
  }
}

// ------------------------------- kNN ---------------------------------------
// One block (256 threads) per (b,g). d in dynamic LDS; 24 argmin+mask passes.
// d = (sl + sx) - 2*dot, each rn, matching |lc|^2+|x|^2-2*einsum.
__global__ __launch_bounds__(256) void knn_kernel(
    const float* __restrict__ xyz, const float* __restrict__ lcz, int N, int G,
    int K, int* __restrict__ knn_idx) {
  extern __shared__ float dsm[];
  __shared__ float redv[4];
  __shared__ int redp[4];
  const int bg = blockIdx.x, b = bg / G, tid = threadIdx.x;
  const float* xb = xyz + (size_t)b * N * 3;
  const float lx = lcz[(size_t)bg * 3 + 0];
  const float ly = lcz[(size_t)bg * 3 + 1];
  const float lz = lcz[(size_t)bg * 3 + 2];
  const float sl = sq3_rn(lx, ly, lz);
  const int NPT = N >> 8;
  for (int i = 0; i < NPT; i++) {
    int p = i * 256 + tid;
    float xx = xb[p * 3 + 0], xy = xb[p * 3 + 1], xz = xb[p * 3 + 2];
    float sx = sq3_rn(xx, xy, xz);
    float dot = __fadd_rn(__fadd_rn(__fmul_rn(lx, xx), __fmul_rn(ly, xy)),
                          __fmul_rn(lz, xz));
    dsm[p] = __fadd_rn(__fadd_rn(sl, sx), -2.0f * dot);
  }
  __syncthreads();
  for (int sel = 0; sel < K; ++sel) {
    float bv = 3e38f;
    int bp = 0x7fffffff;
    for (int i = 0; i < NPT; i++) {
      int p = i * 256 + tid;
      float d = dsm[p];
      if (d < bv) {  // strict < : first (smallest p) min kept
        bv = d;
        bp = p;
      }
    }
#pragma unroll
    for (int o = 32; o > 0; o >>= 1) {
      float ov = __shfl_xor(bv, o);
      int op = __shfl_xor(bp, o);
      if (ov < bv || (ov == bv && op < bp)) {
        bv = ov;
        bp = op;
      }
    }
    if ((tid & 63) == 0) {
      redv[tid >> 6] = bv;
      redp[tid >> 6] = bp;
    }
    __syncthreads();
    bv = redv[0];
    bp = redp[0];
#pragma unroll
    for (int w = 1; w < 4; w++) {
      float ov = redv[w];
      int op = redp[w];
      if (ov < bv || (ov == bv && op < bp)) {
        bv = ov;
        bp = op;
      }
    }
    if (tid == 0) {
      knn_idx[(size_t)bg * K + sel] = bp;
      dsm[bp] = 3e38f;
    }
    __syncthreads();
  }
}

// --------------------------- global std sums --------------------------------
// Accumulate sum / sumsq of (knn_x - lc_x) and (knn_xyz - lc_xyz) in f64.
__global__ __launch_bounds__(256) void stdsum_kernel(
    const float* __restrict__ x_t, const float* __restrict__ xyz,
    const float* __restrict__ lcz, const int* __restrict__ fps_idx,
    const int* __restrict__ knn_idx, int N, int G, int K, int C,
    double* __restrict__ sums /*[4]: sy,sy2,sz,sz2*/) {
  const int bg = blockIdx.x, b = bg / G, tid = threadIdx.x;
  __shared__ int sidx[32];
  if (tid < K) sidx[tid] = knn_idx[(size_t)bg * K + tid];
  __syncthreads();
  const int fg = fps_idx[bg];
  const float* lcrow = x_t + ((size_t)b * N + fg) * C;
  double sy = 0, sy2 = 0, sz = 0, sz2 = 0;
  for (int k = 0; k < K; k++) {
    const float* row = x_t + ((size_t)b * N + sidx[k]) * C;
    for (int c = tid; c < C; c += 256) {
      float v = row[c] - lcrow[c];
      sy += v;
      sy2 += (double)v * (double)v;
    }
  }
  const float l0 = lcz[(size_t)bg * 3 + 0];
  const float l1 = lcz[(size_t)bg * 3 + 1];
  const float l2 = lcz[(size_t)bg * 3 + 2];
  for (int t = tid; t < K * 3; t += 256) {
    int k = t / 3, d = t - 3 * k;
    float lv = (d == 0) ? l0 : ((d == 1) ? l1 : l2);
    float v = xyz[((size_t)b * N + sidx[k]) * 3 + d] - lv;
    sz += v;
    sz2 += (double)v * (double)v;
  }
#pragma unroll
  for (int o = 32; o > 0; o >>= 1) {
    sy += __shfl_xor(sy, o);
    sy2 += __shfl_xor(sy2, o);
    sz += __shfl_xor(sz, o);
    sz2 += __shfl_xor(sz2, o);
  }
  __shared__ double red[4][4];
  if ((tid & 63) == 0) {
    int w = tid >> 6;
    red[w][0] = sy;
    red[w][1] = sy2;
    red[w][2] = sz;
    red[w][3] = sz2;
  }
  __syncthreads();
  if (tid == 0) {
    double a = red[0][0] + red[1][0] + red[2][0] + red[3][0];
    double bq = red[0][1] + red[1][1] + red[2][1] + red[3][1];
    double cc = red[0][2] + red[1][2] + red[2][2] + red[3][2];
    double dd = red[0][3] + red[1][3] + red[2][3] + red[3][3];
    atomicAdd(&sums[0], a);
    atomicAdd(&sums[1], bq);
    atomicAdd(&sums[2], cc);
    atomicAdd(&sums[3], dd);
  }
}

// ------------------------------- LGA + 2*mean_k -----------------------------
// Block per (b,g); thread per output channel c (< Cout).
// c -> (dI, s, f): c = dI*2F + s*F + f  (tr_embed layout).
// knn_x_w[c] = c<Cin ? normalized knn_x : emb7[(c-Cin)%7]
// pos = sc(100*nxyz[dI]/a_f) + sc(100*lc_xyz[dI]/a_f); w=(kxw+pos)*pos.
__global__ void lga_kernel(const float* __restrict__ x_t,
                           const float* __restrict__ xyz,
                           const float* __restrict__ lcz,
                           const int* __restrict__ fps_idx,
                           const int* __restrict__ knn_idx,
                           const double* __restrict__ sums, int N, int G, int K,
                           int Cin, int Cout, int F, double My, double Mz,
                           float* __restrict__ lc_out) {
  const int bg = blockIdx.x, b = bg / G, c = threadIdx.x;
  __shared__ int sidx[32];
  if (c < K) sidx[c] = knn_idx[(size_t)bg * K + c];
  __syncthreads();
  float inv_sx, inv_sz;
  {
    double vy = (sums[1] - sums[0] * sums[0] / My) / (My - 1.0);
    double vz = (sums[3] - sums[2] * sums[2] / Mz) / (Mz - 1.0);
    inv_sx = 1.0f / ((float)sqrt(vy) + 1e-5f);
    inv_sz = 1.0f / ((float)sqrt(vz) + 1e-5f);
  }
  const float l0 = lcz[(size_t)bg * 3 + 0];
  const float l1 = lcz[(size_t)bg * 3 + 1];
  const float l2 = lcz[(size_t)bg * 3 + 2];
  const int fg = fps_idx[bg];
  float lcx = 0.f;
  if (c < Cin) lcx = x_t[((size_t)b * N + fg) * Cin + c];
  const bool active = c < Cout;
  const int twoF = 2 * F;
  int dI = c / twoF;
  if (dI > 2) dI = 2;  // inactive lanes: keep arithmetic safe
  const int rem = c - dI * twoF;
  const int s = rem / F;
  const int f = rem - s * F;
  const float af = expf(6.907755278982137f * (float)f / (float)F);
  const float lv = (dI == 0) ? l0 : ((dI == 1) ? l1 : l2);
  const float arg2 = 100.0f * lv / af;
  const float p2 = s ? cosf(arg2) : sinf(arg2);
  const int j7 = (c >= Cin) ? (c - Cin) % 7 : 0;
  float acc = 0.f;
  for (int k = 0; k < K; k++) {
    const int id = sidx[k];
    const float* q = xyz + ((size_t)b * N + id) * 3;
    float n0 = (q[0] - l0) * inv_sz;
    float n1 = (q[1] - l1) * inv_sz;
    float n2 = (q[2] - l2) * inv_sz;
    float kxw;
    if (c < Cin) {
      kxw = (x_t[((size_t)b * N + id) * Cin + c] - lcx) * inv_sx;
    } else {
      switch (j7) {
        case 0: kxw = n0; break;
        case 1: kxw = n1; break;
        case 2: kxw = n2; break;
        case 3: kxw = n1 * l2 - n2 * l1; break;  // cross(n, l)
        case 4: kxw = n2 * l0 - n0 * l2; break;
        case 5: kxw = n0 * l1 - n1 * l0; break;
        default: kxw = n0 * l0 + n1 * l1 + n2 * l2;  // dot
      }
    }
    float nv = (dI == 0) ? n0 : ((dI == 1) ? n1 : n2);
    float arg1 = 100.0f * nv / af;
    float p1 = s ? cosf(arg1) : sinf(arg1);
    float pos = p1 + p2;
    acc += (kxw + pos) * pos;
  }
  if (active) {
    float m = acc / (float)K;
    lc_out[(size_t)bg * Cout + c] = m + m;  // k_anp + mean == 2*mean
  }
}

// ------------------------------- BN sums ------------------------------------
__global__ void bnsum_kernel(const float* __restrict__ lc, int M, int C,
                             double* __restrict__ out /*[2C]*/) {
  const int c = threadIdx.x;
  if (c >= C) return;
  const int nb = gridDim.x;
  int rows = (M + nb - 1) / nb;
  int r0 = blockIdx.x * rows;
  int r1 = min(M, r0 + rows);
  double s = 0, s2 = 0;
  for (int r = r0; r < r1; r++) {
    float v = lc[(size_t)r * C + c];
    s += v;
    s2 += (double)v * (double)v;
  }
  atomicAdd(&out[c], s);
  atomicAdd(&out[C + c], s2);
}

// ------------------------------- BN + GELU ----------------------------------
__global__ void bnapply_kernel(const float* __restrict__ lc,
                               const double* __restrict__ sums,
                               const float* __restrict__ gamma,
                               const float* __restrict__ beta, int M, int C,
                               int G, int finalT, float* __restrict__ xout) {
  const int bg = blockIdx.x, c = threadIdx.x;
  if (c >= C) return;
  double dm = sums[c] / (double)M;
  double dv = sums[C + c] / (double)M - dm * dm;
  float mean = (float)dm;
  float rstd = 1.0f / sqrtf((float)dv + 1e-5f);
  float v = lc[(size_t)bg * C + c];
  float y = (v - mean) * rstd * gamma[c] + beta[c];
  float ge = 0.5f * y * (1.0f + erff(y * 0.70710678118654752f));
  if (finalT) {
    int b = bg / G, g = bg - b * G;
    xout[((size_t)b * C + c) * G + g] = ge;  // (B,C,G) for d_out
  } else {
    xout[(size_t)bg * C + c] = ge;  // (B,G,C) for next iter gathers
  }
}

// ---------------------------------------------------------------------------
extern "C" void kernel_launch(void* const* d_in, const int* in_sizes, int n_in,
                              void* d_out, int out_size, void* d_ws,
                              size_t ws_size, hipStream_t stream) {
  (void)in_sizes;
  (void)n_in;
  (void)out_size;
  (void)ws_size;
  const float* xyz = (const float*)d_in[0];
  const float* g1 = (const float*)d_in[1];
  const float* b1 = (const float*)d_in[2];
  const float* g2 = (const float*)d_in[3];
  const float* b2 = (const float*)d_in[4];
  float* out = (float*)d_out;

  const int B = 4, N1 = 4096, G1 = 2048, G2 = 1024, K = 24;
  const int C0 = 84, C1 = 168, C2 = 336;

  char* ws = (char*)d_ws;
  size_t off = 0;
  auto alloc = [&](size_t bytes) {
    size_t o = off;
    off += (bytes + 255) & ~(size_t)255;
    return o;
  };
  double* sums1 = (double*)(ws + alloc(4 * 8));
  double* sums2 = (double*)(ws + alloc(4 * 8));
  double* bns1 = (double*)(ws + alloc(2 * C1 * 8));
  double* bns2 = (double*)(ws + alloc(2 * C2 * 8));
  const size_t dbl_bytes = off;  // all f64 accumulators live in [0, off)
  float* x0 = (float*)(ws + alloc((size_t)B * N1 * C0 * 4));
  float* x1 = (float*)(ws + alloc((size_t)B * G1 * C1 * 4));
  float* lcz1 = (float*)(ws + alloc((size_t)B * G1 * 3 * 4));
  float* lcz2 = (float*)(ws + alloc((size_t)B * G2 * 3 * 4));
  int* fps1 = (int*)(ws + alloc((size_t)B * G1 * 4));
  int* fps2 = (int*)(ws + alloc((size_t)B * G2 * 4));
  int* knn1 = (int*)(ws + alloc((size_t)B * G1 * K * 4));
  int* knn2 = (int*)(ws + alloc((size_t)B * G2 * K * 4));
  float* lcb1 = (float*)(ws + alloc((size_t)B * G1 * C1 * 4));
  float* lcb2 = (float*)(ws + alloc((size_t)B * G2 * C2 * 4));

  const int nz = (int)(dbl_bytes / 8);
  zero_kernel<<<(nz + 255) / 256, 256, 0, stream>>>((double*)ws, nz);

  trpos_kernel<<<(B * N1 * 42 + 255) / 256, 256, 0, stream>>>(xyz, B * N1, x0);

  // ---------------- iter 1 ----------------
  fps_kernel<4><<<B, 1024, N1 * 3 * 4, stream>>>(xyz, N1, G1, fps1, lcz1);
  knn_kernel<<<B * G1, 256, N1 * 4, stream>>>(xyz, lcz1, N1, G1, K, knn1);
  stdsum_kernel<<<B * G1, 256, 0, stream>>>(x0, xyz, lcz1, fps1, knn1, N1, G1,
                                            K, C0, sums1);
  lga_kernel<<<B * G1, 192, 0, stream>>>(
      x0, xyz, lcz1, fps1, knn1, sums1, N1, G1, K, C0, C1, 28,
      (double)((size_t)B * G1 * K * C0), (double)((size_t)B * G1 * K * 3),
      lcb1);
  bnsum_kernel<<<64, 192, 0, stream>>>(lcb1, B * G1, C1, bns1);
  bnapply_kernel<<<B * G1, 192, 0, stream>>>(lcb1, bns1, g1, b1, B * G1, C1,
                                             G1, 0, x1);

  // ---------------- iter 2 ----------------
  fps_kernel<2><<<B, 1024, G1 * 3 * 4, stream>>>(lcz1, G1, G2, fps2, lcz2);
  knn_kernel<<<B * G2, 256, G1 * 4, stream>>>(lcz1, lcz2, G1, G2, K, knn2);
  stdsum_kernel<<<B * G2, 256, 0, stream>>>(x1, lcz1, lcz2, fps2, knn2, G1, G2,
                                            K, C1, sums2);
  lga_kernel<<<B * G2, 384, 0, stream>>>(
      x1, lcz1, lcz2, fps2, knn2, sums2, G1, G2, K, C1, C2, 56,
      (double)((size_t)B * G2 * K * C1), (double)((size_t)B * G2 * K * 3),
      lcb2);
  bnsum_kernel<<<64, 384, 0, stream>>>(lcb2, B * G2, C2, bns2);
  bnapply_kernel<<<B * G2, 384, 0, stream>>>(lcb2, bns2, g2, b2, B * G2, C2,
                                             G2, 1, out);
}

// Round 10
// 3239.302 us; speedup vs baseline: 1.6161x; 1.6161x over previous
//
#include <hip/hip_runtime.h>
#include <math.h>

// ---------------------------------------------------------------------------
// EncNP: tr_pos -> 2x { FPS -> kNN -> LGA -> 2*mean_k -> BN+GELU }
// B=4, N=4096, EMBED=84, K=24.  All f32.
// Index decisions (FPS argmax, kNN top-k) replicate reference arithmetic
// bit-exactly (rn ops, no fma contraction, first-index tie-breaks).
// k_anp(w) + w.mean(-1) == 2*mean_k(w)  (e-scalar cancels) -> w never stored.
//
// R8 (v4): FPS 512 threads/block (8 waves). Phase C combine vectorized:
// lane reads slot (lane&7) via one ds_read_b64, then 3 DPP row_ror u64-max
// stages (8 consecutive row positions cover all 8 slots) -> all lanes hold
// the global max. 1 barrier/iter, parity-dbuf slots, LDS-staged xyz.
// ---------------------------------------------------------------------------

__device__ __forceinline__ float sq3_rn(float dx, float dy, float dz) {
  return __fadd_rn(__fadd_rn(__fmul_rn(dx, dx), __fmul_rn(dy, dy)),
                   __fmul_rn(dz, dz));
}

// max over u64 with DPP lane permutation CTRL (all rows/banks, old=src)
template <int CTRL>
__device__ __forceinline__ unsigned long long max64_dpp(unsigned long long pk) {
  int lo = (int)(unsigned)pk, hi = (int)(unsigned)(pk >> 32);
  unsigned olo = (unsigned)__builtin_amdgcn_update_dpp(lo, lo, CTRL, 0xF, 0xF, false);
  unsigned ohi = (unsigned)__builtin_amdgcn_update_dpp(hi, hi, CTRL, 0xF, 0xF, false);
  unsigned long long o = ((unsigned long long)ohi << 32) | olo;
  return o > pk ? o : pk;
}

// full 64-lane max of packed (dist,idx) u64.
// xor1,xor2: quad_perm; xor4,xor8: row_ror (rotate-reduce == max over row16);
// xor16: ds_swizzle; xor32: shfl.
__device__ __forceinline__ unsigned long long wave_max64(unsigned long long pk) {
  pk = max64_dpp<0xB1>(pk);   // quad_perm [1,0,3,2]  == xor1
  pk = max64_dpp<0x4E>(pk);   // quad_perm [2,3,0,1]  == xor2
  pk = max64_dpp<0x124>(pk);  // row_ror:4
  pk = max64_dpp<0x128>(pk);  // row_ror:8  -> row16 max
  {
    unsigned lo = (unsigned)pk, hi = (unsigned)(pk >> 32);
    unsigned olo = (unsigned)__builtin_amdgcn_ds_swizzle((int)lo, 0x401F);
    unsigned ohi = (unsigned)__builtin_amdgcn_ds_swizzle((int)hi, 0x401F);
    unsigned long long o = ((unsigned long long)ohi << 32) | olo;
    if (o > pk) pk = o;
  }
  {
    unsigned long long o = __shfl_xor(pk, 32);
    if (o > pk) pk = o;
  }
  return pk;
}

// ------------------------------- zero accums -------------------------------
__global__ void zero_kernel(double* p, int n) {
  int i = blockIdx.x * blockDim.x + threadIdx.x;
  if (i < n) p[i] = 0.0;
}

// ------------------------------- tr_pos ------------------------------------
// x0[b,n, d*28 + 2f + s] = sin/cos(100*xyz[b,n,d] / 1000^(f/14))
__global__ void trpos_kernel(const float* __restrict__ xyz, int BN,
                             float* __restrict__ x0) {
  int idx = blockIdx.x * blockDim.x + threadIdx.x;
  if (idx >= BN * 42) return;
  int bn = idx / 42;
  int t = idx - bn * 42;
  int dI = t / 14, f = t - dI * 14;
  float v = xyz[(size_t)bn * 3 + dI];
  float af = expf(6.907755278982137f * (float)f * (1.0f / 14.0f));
  float arg = 100.0f * v / af;
  x0[(size_t)bn * 84 + dI * 28 + 2 * f] = sinf(arg);
  x0[(size_t)bn * 84 + dI * 28 + 2 * f + 1] = cosf(arg);
}

// ------------------------------- FPS ---------------------------------------
// One block (512 threads, 8 waves) per batch; point p owned by thread p&511,
// slot p>>9. Exact decision replication: d=((dx^2+dy^2)+dz^2) rn, dist=min,
// global argmax first-index == max over packed (bits(d)<<32 | ~p).
// xyz staged to LDS; centroid via broadcast read. 1 barrier/iter.
// Cross-wave combine: lane reads wave-slot (lane&7) -> 3 DPP row_ror stages.
template <int NPT>  // N == NPT*512
__global__ __launch_bounds__(512) void fps_kernel(
    const float* __restrict__ xyz, int N, int G, int* __restrict__ fps_idx,
    float* __restrict__ lc_out) {
  extern __shared__ float sxyz[];  // N*3
  __shared__ unsigned long long wpk[2][8];
  const int b = blockIdx.x, tid = threadIdx.x;
  const float* xb = xyz + (size_t)b * N * 3;
  for (int t = tid; t < N * 3; t += 512) sxyz[t] = xb[t];
  float px[NPT], py[NPT], pz[NPT], dist[NPT];
#pragma unroll
  for (int i = 0; i < NPT; i++) {
    int p = i * 512 + tid;
    px[i] = xb[p * 3 + 0];
    py[i] = xb[p * 3 + 1];
    pz[i] = xb[p * 3 + 2];
    dist[i] = 1e10f;
  }
  __syncthreads();  // sxyz ready (read-only hereafter)
  int far = 0;
  float cx = sxyz[0], cy = sxyz[1], cz = sxyz[2];
  const int slot = tid & 7;

  for (int g = 0; g < G; ++g) {
    if (tid == 0) {
      fps_idx[b * G + g] = far;
      lc_out[(size_t)(b * G + g) * 3 + 0] = cx;
      lc_out[(size_t)(b * G + g) * 3 + 1] = cy;
      lc_out[(size_t)(b * G + g) * 3 + 2] = cz;
    }
    if (g == G - 1) break;

    // ---- phase A: dist update + thread-local argmax ----
    float bv = -1.0f;
    int bp = 0;
#pragma unroll
    for (int i = 0; i < NPT; i++) {
      float d = sq3_rn(px[i] - cx, py[i] - cy, pz[i] - cz);
      float dm = fminf(dist[i], d);
      dist[i] = dm;
      bool c = dm > bv;  // strict >: ascending p => first max kept
      bv = fmaxf(bv, dm);
      bp = c ? i * 512 + tid : bp;
    }
    // pack: non-negative f32 bits order-monotonic; ~p => min p on tie.
    unsigned long long pk =
        ((unsigned long long)__float_as_uint(bv) << 32) | (unsigned)(~bp);

    // ---- phase B: per-wave 64-lane max ----
    pk = wave_max64(pk);

    // ---- phase C: cross-wave combine, single barrier, parity dbuf ----
    const int par = g & 1;
    if ((tid & 63) == 0) wpk[par][tid >> 6] = pk;
    __syncthreads();
    // lane reads slot (lane&7); row positions m..m+7 (mod 16) cover all 8
    // residues mod 8 -> after ror 1,2,4 every lane holds the global max.
    unsigned long long m = wpk[par][slot];
    m = max64_dpp<0x121>(m);  // row_ror:1
    m = max64_dpp<0x122>(m);  // row_ror:2
    m = max64_dpp<0x124>(m);  // row_ror:4
    far = (int)(~(unsigned)(m & 0xffffffffu));
    cx = sxyz[far * 3 + 0];  // broadcast LDS read
    cy = sxyz[far * 3 + 1];
    cz = sxyz[far * 3 + 2];
  }
}

// ------------------------------- kNN ---------------------------------------
// One block (256 threads) per (b,g). d in dynamic LDS; 24 argmin+mask passes.
// d = (sl + sx) - 2*dot, each rn, matching |lc|^2+|x|^2-2*einsum.
__global__ __launch_bounds__(256) void knn_kernel(
    const float* __restrict__ xyz, const float* __restrict__ lcz, int N, int G,
    int K, int* __restrict__ knn_idx) {
  extern __shared__ float dsm[];
  __shared__ float redv[4];
  __shared__ int redp[4];
  const int bg = blockIdx.x, b = bg / G, tid = threadIdx.x;
  const float* xb = xyz + (size_t)b * N * 3;
  const float lx = lcz[(size_t)bg * 3 + 0];
  const float ly = lcz[(size_t)bg * 3 + 1];
  const float lz = lcz[(size_t)bg * 3 + 2];
  const float sl = sq3_rn(lx, ly, lz);
  const int NPT = N >> 8;
  for (int i = 0; i < NPT; i++) {
    int p = i * 256 + tid;
    float xx = xb[p * 3 + 0], xy = xb[p * 3 + 1], xz = xb[p * 3 + 2];
    float sx = sq3_rn(xx, xy, xz);
    float dot = __fadd_rn(__fadd_rn(__fmul_rn(lx, xx), __fmul_rn(ly, xy)),
                          __fmul_rn(lz, xz));
    dsm[p] = __fadd_rn(__fadd_rn(sl, sx), -2.0f * dot);
  }
  __syncthreads();
  for (int sel = 0; sel < K; ++sel) {
    float bv = 3e38f;
    int bp = 0x7fffffff;
    for (int i = 0; i < NPT; i++) {
      int p = i * 256 + tid;
      float d = dsm[p];
      if (d < bv) {  // strict < : first (smallest p) min kept
        bv = d;
        bp = p;
      }
    }
#pragma unroll
    for (int o = 32; o > 0; o >>= 1) {
      float ov = __shfl_xor(bv, o);
      int op = __shfl_xor(bp, o);
      if (ov < bv || (ov == bv && op < bp)) {
        bv = ov;
        bp = op;
      }
    }
    if ((tid & 63) == 0) {
      redv[tid >> 6] = bv;
      redp[tid >> 6] = bp;
    }
    __syncthreads();
    bv = redv[0];
    bp = redp[0];
#pragma unroll
    for (int w = 1; w < 4; w++) {
      float ov = redv[w];
      int op = redp[w];
      if (ov < bv || (ov == bv && op < bp)) {
        bv = ov;
        bp = op;
      }
    }
    if (tid == 0) {
      knn_idx[(size_t)bg * K + sel] = bp;
      dsm[bp] = 3e38f;
    }
    __syncthreads();
  }
}

// --------------------------- global std sums --------------------------------
// Accumulate sum / sumsq of (knn_x - lc_x) and (knn_xyz - lc_xyz) in f64.
__global__ __launch_bounds__(256) void stdsum_kernel(
    const float* __restrict__ x_t, const float* __restrict__ xyz,
    const float* __restrict__ lcz, const int* __restrict__ fps_idx,
    const int* __restrict__ knn_idx, int N, int G, int K, int C,
    double* __restrict__ sums /*[4]: sy,sy2,sz,sz2*/) {
  const int bg = blockIdx.x, b = bg / G, tid = threadIdx.x;
  __shared__ int sidx[32];
  if (tid < K) sidx[tid] = knn_idx[(size_t)bg * K + tid];
  __syncthreads();
  const int fg = fps_idx[bg];
  const float* lcrow = x_t + ((size_t)b * N + fg) * C;
  double sy = 0, sy2 = 0, sz = 0, sz2 = 0;
  for (int k = 0; k < K; k++) {
    const float* row = x_t + ((size_t)b * N + sidx[k]) * C;
    for (int c = tid; c < C; c += 256) {
      float v = row[c] - lcrow[c];
      sy += v;
      sy2 += (double)v * (double)v;
    }
  }
  const float l0 = lcz[(size_t)bg * 3 + 0];
  const float l1 = lcz[(size_t)bg * 3 + 1];
  const float l2 = lcz[(size_t)bg * 3 + 2];
  for (int t = tid; t < K * 3; t += 256) {
    int k = t / 3, d = t - 3 * k;
    float lv = (d == 0) ? l0 : ((d == 1) ? l1 : l2);
    float v = xyz[((size_t)b * N + sidx[k]) * 3 + d] - lv;
    sz += v;
    sz2 += (double)v * (double)v;
  }
#pragma unroll
  for (int o = 32; o > 0; o >>= 1) {
    sy += __shfl_xor(sy, o);
    sy2 += __shfl_xor(sy2, o);
    sz += __shfl_xor(sz, o);
    sz2 += __shfl_xor(sz2, o);
  }
  __shared__ double red[4][4];
  if ((tid & 63) == 0) {
    int w = tid >> 6;
    red[w][0] = sy;
    red[w][1] = sy2;
    red[w][2] = sz;
    red[w][3] = sz2;
  }
  __syncthreads();
  if (tid == 0) {
    double a = red[0][0] + red[1][0] + red[2][0] + red[3][0];
    double bq = red[0][1] + red[1][1] + red[2][1] + red[3][1];
    double cc = red[0][2] + red[1][2] + red[2][2] + red[3][2];
    double dd = red[0][3] + red[1][3] + red[2][3] + red[3][3];
    atomicAdd(&sums[0], a);
    atomicAdd(&sums[1], bq);
    atomicAdd(&sums[2], cc);
    atomicAdd(&sums[3], dd);
  }
}

// ------------------------------- LGA + 2*mean_k -----------------------------
// Block per (b,g); thread per output channel c (< Cout).
// c -> (dI, s, f): c = dI*2F + s*F + f  (tr_embed layout).
// knn_x_w[c] = c<Cin ? normalized knn_x : emb7[(c-Cin)%7]
// pos = sc(100*nxyz[dI]/a_f) + sc(100*lc_xyz[dI]/a_f); w=(kxw+pos)*pos.
__global__ void lga_kernel(const float* __restrict__ x_t,
                           const float* __restrict__ xyz,
                           const float* __restrict__ lcz,
                           const int* __restrict__ fps_idx,
                           const int* __restrict__ knn_idx,
                           const double* __restrict__ sums, int N, int G, int K,
                           int Cin, int Cout, int F, double My, double Mz,
                           float* __restrict__ lc_out) {
  const int bg = blockIdx.x, b = bg / G, c = threadIdx.x;
  __shared__ int sidx[32];
  if (c < K) sidx[c] = knn_idx[(size_t)bg * K + c];
  __syncthreads();
  float inv_sx, inv_sz;
  {
    double vy = (sums[1] - sums[0] * sums[0] / My) / (My - 1.0);
    double vz = (sums[3] - sums[2] * sums[2] / Mz) / (Mz - 1.0);
    inv_sx = 1.0f / ((float)sqrt(vy) + 1e-5f);
    inv_sz = 1.0f / ((float)sqrt(vz) + 1e-5f);
  }
  const float l0 = lcz[(size_t)bg * 3 + 0];
  const float l1 = lcz[(size_t)bg * 3 + 1];
  const float l2 = lcz[(size_t)bg * 3 + 2];
  const int fg = fps_idx[bg];
  float lcx = 0.f;
  if (c < Cin) lcx = x_t[((size_t)b * N + fg) * Cin + c];
  const bool active = c < Cout;
  const int twoF = 2 * F;
  int dI = c / twoF;
  if (dI > 2) dI = 2;  // inactive lanes: keep arithmetic safe
  const int rem = c - dI * twoF;
  const int s = rem / F;
  const int f = rem - s * F;
  const float af = expf(6.907755278982137f * (float)f / (float)F);
  const float lv = (dI == 0) ? l0 : ((dI == 1) ? l1 : l2);
  const float arg2 = 100.0f * lv / af;
  const float p2 = s ? cosf(arg2) : sinf(arg2);
  const int j7 = (c >= Cin) ? (c - Cin) % 7 : 0;
  float acc = 0.f;
  for (int k = 0; k < K; k++) {
    const int id = sidx[k];
    const float* q = xyz + ((size_t)b * N + id) * 3;
    float n0 = (q[0] - l0) * inv_sz;
    float n1 = (q[1] - l1) * inv_sz;
    float n2 = (q[2] - l2) * inv_sz;
    float kxw;
    if (c < Cin) {
      kxw = (x_t[((size_t)b * N + id) * Cin + c] - lcx) * inv_sx;
    } else {
      switch (j7) {
        case 0: kxw = n0; break;
        case 1: kxw = n1; break;
        case 2: kxw = n2; break;
        case 3: kxw = n1 * l2 - n2 * l1; break;  // cross(n, l)
        case 4: kxw = n2 * l0 - n0 * l2; break;
        case 5: kxw = n0 * l1 - n1 * l0; break;
        default: kxw = n0 * l0 + n1 * l1 + n2 * l2;  // dot
      }
    }
    float nv = (dI == 0) ? n0 : ((dI == 1) ? n1 : n2);
    float arg1 = 100.0f * nv / af;
    float p1 = s ? cosf(arg1) : sinf(arg1);
    float pos = p1 + p2;
    acc += (kxw + pos) * pos;
  }
  if (active) {
    float m = acc / (float)K;
    lc_out[(size_t)bg * Cout + c] = m + m;  // k_anp + mean == 2*mean
  }
}

// ------------------------------- BN sums ------------------------------------
__global__ void bnsum_kernel(const float* __restrict__ lc, int M, int C,
                             double* __restrict__ out /*[2C]*/) {
  const int c = threadIdx.x;
  if (c >= C) return;
  const int nb = gridDim.x;
  int rows = (M + nb - 1) / nb;
  int r0 = blockIdx.x * rows;
  int r1 = min(M, r0 + rows);
  double s = 0, s2 = 0;
  for (int r = r0; r < r1; r++) {
    float v = lc[(size_t)r * C + c];
    s += v;
    s2 += (double)v * (double)v;
  }
  atomicAdd(&out[c], s);
  atomicAdd(&out[C + c], s2);
}

// ------------------------------- BN + GELU ----------------------------------
__global__ void bnapply_kernel(const float* __restrict__ lc,
                               const double* __restrict__ sums,
                               const float* __restrict__ gamma,
                               const float* __restrict__ beta, int M, int C,
                               int G, int finalT, float* __restrict__ xout) {
  const int bg = blockIdx.x, c = threadIdx.x;
  if (c >= C) return;
  double dm = sums[c] / (double)M;
  double dv = sums[C + c] / (double)M - dm * dm;
  float mean = (float)dm;
  float rstd = 1.0f / sqrtf((float)dv + 1e-5f);
  float v = lc[(size_t)bg * C + c];
  float y = (v - mean) * rstd * gamma[c] + beta[c];
  float ge = 0.5f * y * (1.0f + erff(y * 0.70710678118654752f));
  if (finalT) {
    int b = bg / G, g = bg - b * G;
    xout[((size_t)b * C + c) * G + g] = ge;  // (B,C,G) for d_out
  } else {
    xout[(size_t)bg * C + c] = ge;  // (B,G,C) for next iter gathers
  }
}

// ---------------------------------------------------------------------------
extern "C" void kernel_launch(void* const* d_in, const int* in_sizes, int n_in,
                              void* d_out, int out_size, void* d_ws,
                              size_t ws_size, hipStream_t stream) {
  (void)in_sizes;
  (void)n_in;
  (void)out_size;
  (void)ws_size;
  const float* xyz = (const float*)d_in[0];
  const float* g1 = (const float*)d_in[1];
  const float* b1 = (const float*)d_in[2];
  const float* g2 = (const float*)d_in[3];
  const float* b2 = (const float*)d_in[4];
  float* out = (float*)d_out;

  const int B = 4, N1 = 4096, G1 = 2048, G2 = 1024, K = 24;
  const int C0 = 84, C1 = 168, C2 = 336;

  char* ws = (char*)d_ws;
  size_t off = 0;
  auto alloc = [&](size_t bytes) {
    size_t o = off;
    off += (bytes + 255) & ~(size_t)255;
    return o;
  };
  double* sums1 = (double*)(ws + alloc(4 * 8));
  double* sums2 = (double*)(ws + alloc(4 * 8));
  double* bns1 = (double*)(ws + alloc(2 * C1 * 8));
  double* bns2 = (double*)(ws + alloc(2 * C2 * 8));
  const size_t dbl_bytes = off;  // all f64 accumulators live in [0, off)
  float* x0 = (float*)(ws + alloc((size_t)B * N1 * C0 * 4));
  float* x1 = (float*)(ws + alloc((size_t)B * G1 * C1 * 4));
  float* lcz1 = (float*)(ws + alloc((size_t)B * G1 * 3 * 4));
  float* lcz2 = (float*)(ws + alloc((size_t)B * G2 * 3 * 4));
  int* fps1 = (int*)(ws + alloc((size_t)B * G1 * 4));
  int* fps2 = (int*)(ws + alloc((size_t)B * G2 * 4));
  int* knn1 = (int*)(ws + alloc((size_t)B * G1 * K * 4));
  int* knn2 = (int*)(ws + alloc((size_t)B * G2 * K * 4));
  float* lcb1 = (float*)(ws + alloc((size_t)B * G1 * C1 * 4));
  float* lcb2 = (float*)(ws + alloc((size_t)B * G2 * C2 * 4));

  const int nz = (int)(dbl_bytes / 8);
  zero_kernel<<<(nz + 255) / 256, 256, 0, stream>>>((double*)ws, nz);

  trpos_kernel<<<(B * N1 * 42 + 255) / 256, 256, 0, stream>>>(xyz, B * N1, x0);

  // ---------------- iter 1 ----------------
  fps_kernel<8><<<B, 512, N1 * 3 * 4, stream>>>(xyz, N1, G1, fps1, lcz1);
  knn_kernel<<<B * G1, 256, N1 * 4, stream>>>(xyz, lcz1, N1, G1, K, knn1);
  stdsum_kernel<<<B * G1, 256, 0, stream>>>(x0, xyz, lcz1, fps1, knn1, N1, G1,
                                            K, C0, sums1);
  lga_kernel<<<B * G1, 192, 0, stream>>>(
      x0, xyz, lcz1, fps1, knn1, sums1, N1, G1, K, C0, C1, 28,
      (double)((size_t)B * G1 * K * C0), (double)((size_t)B * G1 * K * 3),
      lcb1);
  bnsum_kernel<<<64, 192, 0, stream>>>(lcb1, B * G1, C1, bns1);
  bnapply_kernel<<<B * G1, 192, 0, stream>>>(lcb1, bns1, g1, b1, B * G1, C1,
                                             G1, 0, x1);

  // ---------------- iter 2 ----------------
  fps_kernel<4><<<B, 512, G1 * 3 * 4, stream>>>(lcz1, G1, G2, fps2, lcz2);
  knn_kernel<<<B * G2, 256, G1 * 4, stream>>>(lcz1, lcz2, G1, G2, K, knn2);
  stdsum_kernel<<<B * G2, 256, 0, stream>>>(x1, lcz1, lcz2, fps2, knn2, G1, G2,
                                            K, C1, sums2);
  lga_kernel<<<B * G2, 384, 0, stream>>>(
      x1, lcz1, lcz2, fps2, knn2, sums2, G1, G2, K, C1, C2, 56,
      (double)((size_t)B * G2 * K * C1), (double)((size_t)B * G2 * K * 3),
      lcb2);
  bnsum_kernel<<<64, 384, 0, stream>>>(lcb2, B * G2, C2, bns2);
  bnapply_kernel<<<B * G2, 384, 0, stream>>>(lcb2, bns2, g2, b2, B * G2, C2,
                                             G2, 1, out);
}